// Round 12
// baseline (256.167 us; speedup 1.0000x reference)
//
#include <hip/hip_runtime.h>
#include <cstdint>

#define N_NODES 100000
#define N_EDGES 1600000
#define NBUCKET 196          // ceil(N_NODES / 512)
#define NPB_SHIFT 9
#define NPB 512              // nodes per bucket
#define P1_CHUNK 2048        // edges per partition block (16KB stage -> 6 blk/CU)
#define NB_P1 782            // ceil(N_EDGES / P1_CHUNK)
#define NBG 1563             // gemm blocks (64 rows each)
#define BSW_CAP 9216         // per-bucket edge capacity (mean 8163, sigma~90)
#define CSR_CAP 17408        // per-bucket padded csr capacity (raw + 512*15 + slack)

typedef int iv4 __attribute__((ext_vector_type(4)));
typedef unsigned short usv8 __attribute__((ext_vector_type(8)));

__device__ __forceinline__ unsigned short f2bf(float x) {   // RNE f32->bf16
    unsigned u = __float_as_uint(x);
    unsigned r = ((u >> 16) & 1u) + 0x7FFFu;
    return (unsigned short)((u + r) >> 16);
}
__device__ __forceinline__ float bf2f(unsigned short v) {
    return __uint_as_float((unsigned)v << 16);
}

// ---------------- bucketed CSR build (no global data atomics) ----------------

__global__ __launch_bounds__(256) void k_init(int* __restrict__ gcursor) {
    int i = threadIdx.x;
    if (i < NBUCKET) gcursor[i] = i * BSW_CAP;
}

struct P1Shared {
    uint2 stage[P1_CHUNK];              // ((dloc<<17)|src, w) bucket-ordered   16 KB
    unsigned char stage_bkt[P1_CHUNK];  // bucket id per slot                    2 KB
    int cnt[256];
    int lbase[256];
    int gbase[256];
};
struct GemmShared { float sW[64][65]; float sX[32][65]; };   // 24.9 KB

// P1: partition edges into bucket-ordered bsw=(dloc|src, w); fused gemm1
__global__ __launch_bounds__(256) void k_p1gemm(const int* __restrict__ dst,
                                                const int* __restrict__ srcarr,
                                                const float* __restrict__ ea,
                                                int* gcursor,
                                                uint2* __restrict__ bsw,
                                                const float* __restrict__ X,
                                                const float* __restrict__ W,
                                                float* __restrict__ Y) {
    __shared__ union { P1Shared p; GemmShared g; } sm;
    int t = threadIdx.x;
    if (blockIdx.x < NB_P1) {
        sm.p.cnt[t] = 0;
        __syncthreads();
        int e0 = blockIdx.x * P1_CHUNK;
        unsigned int dr[8];                        // (d<<12)|rank (rank<2048)
#pragma unroll
        for (int i = 0; i < 2; ++i) {
            int idx = e0 + (t + i * 256) * 4;
            if (idx + 3 < N_EDGES) {
                int4 d4 = *reinterpret_cast<const int4*>(&dst[idx]);
                int r0 = atomicAdd(&sm.p.cnt[d4.x >> NPB_SHIFT], 1);
                int r1 = atomicAdd(&sm.p.cnt[d4.y >> NPB_SHIFT], 1);
                int r2 = atomicAdd(&sm.p.cnt[d4.z >> NPB_SHIFT], 1);
                int r3 = atomicAdd(&sm.p.cnt[d4.w >> NPB_SHIFT], 1);
                dr[i * 4 + 0] = ((unsigned)d4.x << 12) | (unsigned)r0;
                dr[i * 4 + 1] = ((unsigned)d4.y << 12) | (unsigned)r1;
                dr[i * 4 + 2] = ((unsigned)d4.z << 12) | (unsigned)r2;
                dr[i * 4 + 3] = ((unsigned)d4.w << 12) | (unsigned)r3;
            } else {
#pragma unroll
                for (int k = 0; k < 4; ++k) dr[i * 4 + k] = 0xFFFFFFFFu;
            }
        }
        __syncthreads();
        int v = sm.p.cnt[t];
        sm.p.lbase[t] = v;
        __syncthreads();
        for (int off = 1; off < 256; off <<= 1) {
            int u = (t >= off) ? sm.p.lbase[t - off] : 0;
            __syncthreads();
            sm.p.lbase[t] += u;
            __syncthreads();
        }
        int ex = sm.p.lbase[t] - v;
        if (t < NBUCKET) sm.p.gbase[t] = atomicAdd(&gcursor[t], v);
        __syncthreads();
        sm.p.lbase[t] = ex;
        __syncthreads();
#pragma unroll
        for (int i = 0; i < 2; ++i) {
            int idx = e0 + (t + i * 256) * 4;
            if (idx + 3 < N_EDGES) {
                int4 s4 = *reinterpret_cast<const int4*>(&srcarr[idx]);
                float4 a4 = *reinterpret_cast<const float4*>(&ea[idx]);
                float t0 = a4.x * (1.0f / 200.0f), t1 = a4.y * (1.0f / 200.0f);
                float t2 = a4.z * (1.0f / 200.0f), t3 = a4.w * (1.0f / 200.0f);
                int   ss[4] = {s4.x, s4.y, s4.z, s4.w};
                float ww[4] = {__expf(-t0 * t0), __expf(-t1 * t1),
                               __expf(-t2 * t2), __expf(-t3 * t3)};
#pragma unroll
                for (int k = 0; k < 4; ++k) {
                    unsigned drv = dr[i * 4 + k];
                    int d = drv >> 12, r = drv & 0xFFF;
                    int b = d >> NPB_SHIFT, dloc = d & (NPB - 1);
                    int pos = sm.p.lbase[b] + r;
                    sm.p.stage[pos] = make_uint2(((unsigned)dloc << 17) | (unsigned)ss[k],
                                                 __float_as_uint(ww[k]));
                    sm.p.stage_bkt[pos] = (unsigned char)b;
                }
            }
        }
        __syncthreads();
        int n_valid = min(P1_CHUNK, N_EDGES - e0);
        for (int j = t; j < n_valid; j += 256) {
            int b = sm.p.stage_bkt[j];
            int pos = sm.p.gbase[b] + (j - sm.p.lbase[b]);
            bsw[pos] = sm.p.stage[j];
        }
        return;
    }
    // ---- gemm1: Y = X @ W, two 32-row passes with resident sW ----
    int rb = (blockIdx.x - NB_P1) * 64;
#pragma unroll
    for (int i = 0; i < 16; ++i) {
        int idx = t + i * 256;
        sm.g.sW[idx >> 6][idx & 63] = W[idx];
    }
    for (int half = 0; half < 2; ++half) {
        int rb2 = rb + half * 32;
        __syncthreads();
#pragma unroll
        for (int i = 0; i < 8; ++i) {
            int idx = t + i * 256;
            int r = idx >> 6, c = idx & 63;
            int gr = rb2 + r;
            sm.g.sX[r][c] = (gr < N_NODES) ? X[(size_t)gr * 64 + c] : 0.0f;
        }
        __syncthreads();
        int tr = (t >> 4) * 2;
        int tc = (t & 15) * 4;
        float acc[2][4] = {{0.f, 0.f, 0.f, 0.f}, {0.f, 0.f, 0.f, 0.f}};
#pragma unroll 8
        for (int k = 0; k < 64; ++k) {
            float xv0 = sm.g.sX[tr][k], xv1 = sm.g.sX[tr + 1][k];
            float wv[4];
#pragma unroll
            for (int j = 0; j < 4; ++j) wv[j] = sm.g.sW[k][tc + j];
#pragma unroll
            for (int j = 0; j < 4; ++j) {
                acc[0][j] = fmaf(xv0, wv[j], acc[0][j]);
                acc[1][j] = fmaf(xv1, wv[j], acc[1][j]);
            }
        }
#pragma unroll
        for (int i = 0; i < 2; ++i) {
            int gr = rb2 + tr + i;
            if (gr < N_NODES) {
                float4 v = make_float4(acc[i][0], acc[i][1], acc[i][2], acc[i][3]);
                *reinterpret_cast<float4*>(&Y[(size_t)gr * 64 + tc]) = v;
            }
        }
    }
}

// P2: pure-streaming per-bucket build; rows padded to multiple of 16
__global__ __launch_bounds__(1024) void k_p2(const uint2* __restrict__ bsw,
                                             const int* __restrict__ gcursor,
                                             int2* __restrict__ rowinfo,
                                             int2* __restrict__ csr,
                                             float* __restrict__ dinv) {
    __shared__ int cnt[NPB];
    __shared__ int prp[NPB];
    __shared__ int cur[NPB];
    __shared__ float degw[NPB];
    int t = threadIdx.x;
    int b = blockIdx.x;
    if (t < NPB) { cnt[t] = 0; degw[t] = 0.0f; }
    __syncthreads();
    int segb = b * BSW_CAP;
    int sege = gcursor[b];                 // = segb + bucket count
    int pbase = b * CSR_CAP;
    for (int j = segb + t; j < sege; j += 1024)
        atomicAdd(&cnt[bsw[j].x >> 17], 1);
    __syncthreads();
    int raw = (t < NPB) ? cnt[t] : 0;
    int pad = (raw + 15) & ~15;
    if (t < NPB) prp[t] = pad;
    __syncthreads();
    for (int off = 1; off < NPB; off <<= 1) {
        int u = (t >= off && t < NPB) ? prp[t - off] : 0;
        __syncthreads();
        if (t < NPB) prp[t] += u;
        __syncthreads();
    }
    if (t < NPB) { prp[t] -= pad; cur[t] = prp[t]; }   // exclusive base + cursor
    __syncthreads();
    int node = (b << NPB_SHIFT) + t;
    if (t < NPB && node < N_NODES)
        rowinfo[node] = make_int2(pbase + prp[t], pad >> 4);
    for (int j = segb + t; j < sege; j += 1024) {
        uint2 v = bsw[j];
        int dloc = (int)(v.x >> 17);
        int src  = (int)(v.x & 0x1FFFFu);
        int pos = atomicAdd(&cur[dloc], 1);
        csr[pbase + pos] = make_int2(src, (int)v.y);
        atomicAdd(&degw[dloc], __uint_as_float(v.y));
    }
    __syncthreads();
    if (t < NPB && node < N_NODES) {
        dinv[node] = rsqrtf(1.0f + degw[t]);
        int begin = pbase + prp[t];
        for (int j = raw; j < pad; ++j) csr[begin + j] = make_int2(node, 0);
    }
}

// XWs[i,f] = bf16(dinv[i] * XW[i,f])
__global__ __launch_bounds__(256) void k_scale(const float* __restrict__ XW,
                                               const float* __restrict__ dinv,
                                               unsigned short* __restrict__ XWs) {
    int g = blockIdx.x * 256 + threadIdx.x;
    int base = g * 8;
    if (base >= N_NODES * 64) return;
    float d = dinv[base >> 6];
    float4 v0 = *reinterpret_cast<const float4*>(XW + base);
    float4 v1 = *reinterpret_cast<const float4*>(XW + base + 4);
    usv8 r;
    r.s0 = f2bf(d * v0.x); r.s1 = f2bf(d * v0.y);
    r.s2 = f2bf(d * v0.z); r.s3 = f2bf(d * v0.w);
    r.s4 = f2bf(d * v1.x); r.s5 = f2bf(d * v1.y);
    r.s6 = f2bf(d * v1.z); r.s7 = f2bf(d * v1.w);
    *reinterpret_cast<usv8*>(XWs + base) = r;
}

// ---------------- dense compute ----------------

// gemm2: Y = X @ W with epilogue  XWs[gr,:] = bf16(dinv[gr] * Y[gr,:])
__global__ __launch_bounds__(256) void k_gemm64s(const float* __restrict__ X,
                                                 const float* __restrict__ W,
                                                 const float* __restrict__ dinv,
                                                 unsigned short* __restrict__ XWs) {
    __shared__ float sX[64][65];
    __shared__ float sW[64][65];
    int t = threadIdx.x;
    int rb = blockIdx.x * 64;
#pragma unroll
    for (int i = 0; i < 16; ++i) {
        int idx = t + i * 256;
        int r = idx >> 6, c = idx & 63;
        sW[r][c] = W[idx];
        int gr = rb + r;
        sX[r][c] = (gr < N_NODES) ? X[(size_t)gr * 64 + c] : 0.0f;
    }
    __syncthreads();
    int tr = (t >> 4) * 4;
    int tc = (t & 15) * 4;
    float acc[4][4] = {{0.f}};
#pragma unroll 8
    for (int k = 0; k < 64; ++k) {
        float xv[4], wv[4];
#pragma unroll
        for (int i = 0; i < 4; ++i) xv[i] = sX[tr + i][k];
#pragma unroll
        for (int j = 0; j < 4; ++j) wv[j] = sW[k][tc + j];
#pragma unroll
        for (int i = 0; i < 4; ++i)
#pragma unroll
            for (int j = 0; j < 4; ++j) acc[i][j] = fmaf(xv[i], wv[j], acc[i][j]);
    }
#pragma unroll
    for (int i = 0; i < 4; ++i) {
        int gr = rb + tr + i;
        if (gr < N_NODES) {
            float d = dinv[gr];
            ushort4 v;
            v.x = f2bf(d * acc[i][0]); v.y = f2bf(d * acc[i][1]);
            v.z = f2bf(d * acc[i][2]); v.w = f2bf(d * acc[i][3]);
            *reinterpret_cast<ushort4*>(&XWs[((unsigned)gr << 6) + tc]) = v;
        }
    }
}

// one wave per node, PAIR-GATHER: lane q=l&31 holds features {2q,2q+1};
// h=l>>5 selects even/odd edge slots -> one dword gather serves 2 edges.
// CSR path scalarized (s_load via K$); rows padded to 16 (8 loads in flight).
// MODE 0: OUT row f32;  MODE 1: fused W3 dot -> OUT[i] scalar
template <int MODE>
__global__ __launch_bounds__(256) void k_agg64(const unsigned short* __restrict__ XWs,
                                               const int* __restrict__ csr_i,
                                               const int2* __restrict__ rowinfo,
                                               const float* __restrict__ dinv,
                                               const float* __restrict__ bias,
                                               float* __restrict__ OUT,
                                               const float* __restrict__ W3) {
    int wid0 = (blockIdx.x * 256 + threadIdx.x) >> 6;
    if (wid0 >= N_NODES) return;                     // wave-uniform exit
    int wid = __builtin_amdgcn_readfirstlane(wid0);
    unsigned lane = threadIdx.x & 63;
    unsigned q = lane & 31;
    unsigned h = lane >> 5;
    float di = dinv[wid];
    unsigned sv = *reinterpret_cast<const unsigned*>(&XWs[((unsigned)wid << 6) + 2u * q]);
    int2 ri = rowinfo[wid];
    int rbase = __builtin_amdgcn_readfirstlane(ri.x);
    int nb    = __builtin_amdgcn_readfirstlane(ri.y);
    const int* pc = csr_i + ((size_t)rbase * 2);
    float a0 = 0.f, a1 = 0.f, b0 = 0.f, b1 = 0.f;
    float c0 = 0.f, c1 = 0.f, d0 = 0.f, d1 = 0.f;
    for (int it = 0; it < nb; ++it, pc += 32) {      // 16 edges per iter
        int e0 = h ? pc[2]  : pc[0];   float f0 = __int_as_float(h ? pc[3]  : pc[1]);
        int e1 = h ? pc[6]  : pc[4];   float f1 = __int_as_float(h ? pc[7]  : pc[5]);
        int e2 = h ? pc[10] : pc[8];   float f2 = __int_as_float(h ? pc[11] : pc[9]);
        int e3 = h ? pc[14] : pc[12];  float f3 = __int_as_float(h ? pc[15] : pc[13]);
        int e4 = h ? pc[18] : pc[16];  float f4 = __int_as_float(h ? pc[19] : pc[17]);
        int e5 = h ? pc[22] : pc[20];  float f5 = __int_as_float(h ? pc[23] : pc[21]);
        int e6 = h ? pc[26] : pc[24];  float f6 = __int_as_float(h ? pc[27] : pc[25]);
        int e7 = h ? pc[30] : pc[28];  float f7 = __int_as_float(h ? pc[31] : pc[29]);
        unsigned v0 = *reinterpret_cast<const unsigned*>(&XWs[((unsigned)e0 << 6) + 2u * q]);
        unsigned v1 = *reinterpret_cast<const unsigned*>(&XWs[((unsigned)e1 << 6) + 2u * q]);
        unsigned v2 = *reinterpret_cast<const unsigned*>(&XWs[((unsigned)e2 << 6) + 2u * q]);
        unsigned v3 = *reinterpret_cast<const unsigned*>(&XWs[((unsigned)e3 << 6) + 2u * q]);
        unsigned v4 = *reinterpret_cast<const unsigned*>(&XWs[((unsigned)e4 << 6) + 2u * q]);
        unsigned v5 = *reinterpret_cast<const unsigned*>(&XWs[((unsigned)e5 << 6) + 2u * q]);
        unsigned v6 = *reinterpret_cast<const unsigned*>(&XWs[((unsigned)e6 << 6) + 2u * q]);
        unsigned v7 = *reinterpret_cast<const unsigned*>(&XWs[((unsigned)e7 << 6) + 2u * q]);
        a0 = fmaf(f0, __uint_as_float(v0 << 16), a0);
        a1 = fmaf(f0, __uint_as_float(v0 & 0xFFFF0000u), a1);
        b0 = fmaf(f1, __uint_as_float(v1 << 16), b0);
        b1 = fmaf(f1, __uint_as_float(v1 & 0xFFFF0000u), b1);
        c0 = fmaf(f2, __uint_as_float(v2 << 16), c0);
        c1 = fmaf(f2, __uint_as_float(v2 & 0xFFFF0000u), c1);
        d0 = fmaf(f3, __uint_as_float(v3 << 16), d0);
        d1 = fmaf(f3, __uint_as_float(v3 & 0xFFFF0000u), d1);
        a0 = fmaf(f4, __uint_as_float(v4 << 16), a0);
        a1 = fmaf(f4, __uint_as_float(v4 & 0xFFFF0000u), a1);
        b0 = fmaf(f5, __uint_as_float(v5 << 16), b0);
        b1 = fmaf(f5, __uint_as_float(v5 & 0xFFFF0000u), b1);
        c0 = fmaf(f6, __uint_as_float(v6 << 16), c0);
        c1 = fmaf(f6, __uint_as_float(v6 & 0xFFFF0000u), c1);
        d0 = fmaf(f7, __uint_as_float(v7 << 16), d0);
        d1 = fmaf(f7, __uint_as_float(v7 & 0xFFFF0000u), d1);
    }
    float e0sum = (a0 + b0) + (c0 + d0);
    float e1sum = (a1 + b1) + (c1 + d1);
    e0sum += __shfl_xor(e0sum, 32, 64);   // combine even/odd halves
    e1sum += __shfl_xor(e1sum, 32, 64);
    float2 bi = *reinterpret_cast<const float2*>(&bias[2u * q]);
    float acc0 = di * (__uint_as_float(sv << 16) + e0sum) + bi.x;
    float acc1 = di * (__uint_as_float(sv & 0xFFFF0000u) + e1sum) + bi.y;
    acc0 = fmaxf(acc0, 0.0f);
    acc1 = fmaxf(acc1, 0.0f);
    if (MODE == 0) {
        if (h == 0) {
            *reinterpret_cast<float2*>(&OUT[((unsigned)wid << 6) + 2u * q]) =
                make_float2(acc0, acc1);
        }
    } else {
        float2 w3 = *reinterpret_cast<const float2*>(&W3[2u * q]);
        float v = acc0 * w3.x + acc1 * w3.y;   // duplicated across halves
#pragma unroll
        for (int off = 32; off > 0; off >>= 1) v += __shfl_down(v, off, 64);
        if (lane == 0) OUT[wid] = di * v * 0.5f;   // halve the duplication
    }
}

// out[i] = b3 + di*(xw3s[i] + sum_e w_e*xw3s[src_e])   (16-padded rows)
__global__ __launch_bounds__(256) void k_agg_scalar(const float* __restrict__ xw3s,
                                                    const int2* __restrict__ csr,
                                                    const int2* __restrict__ rowinfo,
                                                    const float* __restrict__ dinv,
                                                    const float* __restrict__ b3,
                                                    float* __restrict__ out) {
    int i = blockIdx.x * 256 + threadIdx.x;
    if (i >= N_NODES) return;
    float di = dinv[i];
    int2 ri = rowinfo[i];
    const iv4* p = reinterpret_cast<const iv4*>(csr + ri.x);
    int nb = ri.y;
    float a0 = 0.f, a1 = 0.f, a2 = 0.f, a3 = 0.f;
    for (int it = 0; it < nb; ++it, p += 8) {   // 16 edges per iter
#pragma unroll
        for (int u = 0; u < 2; ++u) {
            iv4 q0 = __builtin_nontemporal_load(p + 4 * u);
            iv4 q1 = __builtin_nontemporal_load(p + 4 * u + 1);
            iv4 q2 = __builtin_nontemporal_load(p + 4 * u + 2);
            iv4 q3 = __builtin_nontemporal_load(p + 4 * u + 3);
            a0 = fmaf(__int_as_float(q0.y), xw3s[q0.x], a0);
            a1 = fmaf(__int_as_float(q0.w), xw3s[q0.z], a1);
            a2 = fmaf(__int_as_float(q1.y), xw3s[q1.x], a2);
            a3 = fmaf(__int_as_float(q1.w), xw3s[q1.z], a3);
            a0 = fmaf(__int_as_float(q2.y), xw3s[q2.x], a0);
            a1 = fmaf(__int_as_float(q2.w), xw3s[q2.z], a1);
            a2 = fmaf(__int_as_float(q3.y), xw3s[q3.x], a2);
            a3 = fmaf(__int_as_float(q3.w), xw3s[q3.z], a3);
        }
    }
    out[i] = di * (xw3s[i] + (a0 + a1) + (a2 + a3)) + b3[0];
}

// ---------------- launch ----------------

extern "C" void kernel_launch(void* const* d_in, const int* in_sizes, int n_in,
                              void* d_out, int out_size, void* d_ws, size_t ws_size,
                              hipStream_t stream) {
    const float* x  = (const float*)d_in[0];
    const int*   ei = (const int*)d_in[1];     // int32 per harness contract
    const float* ea = (const float*)d_in[2];
    const float* W1 = (const float*)d_in[3];
    const float* b1 = (const float*)d_in[4];
    const float* W2 = (const float*)d_in[5];
    const float* b2 = (const float*)d_in[6];
    const float* W3 = (const float*)d_in[7];
    const float* b3 = (const float*)d_in[8];
    float* out = (float*)d_out;
    const int* srcarr = ei;
    const int* dstarr = ei + N_EDGES;

    char* ws = (char*)d_ws;
    size_t off = 0;
    auto alloc = [&](size_t bytes) -> void* {
        void* p = ws + off;
        off = (off + bytes + 255) & ~(size_t)255;
        return p;
    };
    float* dinv     = (float*)alloc((size_t)N_NODES * 4);
    int2*  rowinfo  = (int2*) alloc((size_t)N_NODES * 8);
    int*   gcursor  = (int*)  alloc(NBUCKET * 4);
    float* xw3s     = (float*)alloc((size_t)N_NODES * 4);
    // bsw (14.5 MB; dead after P2) shares its region with XWs1 (12.8 MB)
    void*  region   = alloc((size_t)NBUCKET * BSW_CAP * 8);
    uint2*          bsw  = (uint2*)region;
    unsigned short* XWs1 = (unsigned short*)region;
    int2*  csr      = (int2*) alloc((size_t)NBUCKET * CSR_CAP * 8);
    float* bufA     = (float*)alloc((size_t)N_NODES * 64 * 4);   // gemm1 out; reused as XWs2
    float* bufB     = (float*)alloc((size_t)N_NODES * 64 * 4);
    unsigned short* XWs2 = (unsigned short*)bufA;  // bufA dead after k_scale reads it

    const int nbW = N_NODES / 4;             // 25000
    const int nbN = (N_NODES + 255) / 256;   // 391
    const int nbS = (N_NODES * 64 / 8 + 255) / 256;   // 3125 scale blocks

    k_init<<<1, 256, 0, stream>>>(gcursor);
    k_p1gemm<<<NB_P1 + NBG, 256, 0, stream>>>(dstarr, srcarr, ea, gcursor,
                                              bsw, x, W1, bufA);
    k_p2<<<NBUCKET, 1024, 0, stream>>>(bsw, gcursor, rowinfo, csr, dinv);
    k_scale<<<nbS, 256, 0, stream>>>(bufA, dinv, XWs1);   // overwrites bsw region

    k_agg64<0><<<nbW, 256, 0, stream>>>(XWs1, (const int*)csr, rowinfo, dinv, b1, bufB, nullptr);
    k_gemm64s<<<NBG, 256, 0, stream>>>(bufB, W2, dinv, XWs2);   // overwrites bufA
    k_agg64<1><<<nbW, 256, 0, stream>>>(XWs2, (const int*)csr, rowinfo, dinv, b2, xw3s, W3);
    k_agg_scalar<<<nbN, 256, 0, stream>>>(xw3s, csr, rowinfo, dinv, b3, out);
}

// Round 13
// 206.740 us; speedup vs baseline: 1.2391x; 1.2391x over previous
//
#include <hip/hip_runtime.h>
#include <cstdint>

#define N_NODES 100000
#define N_EDGES 1600000
#define NBUCKET 196          // ceil(N_NODES / 512)
#define NPB_SHIFT 9
#define NPB 512              // nodes per bucket
#define P1_CHUNK 4096        // edges per partition block
#define NB_P1 391            // ceil(N_EDGES / P1_CHUNK)
#define NBG 1563             // gemm blocks (64 rows each)
#define BSW_CAP 9216         // per-bucket edge capacity (mean 8163, sigma~90)
#define CSR_CAP 12800        // per-bucket padded csr capacity (raw + 512*7 + slack)

typedef int iv4 __attribute__((ext_vector_type(4)));
typedef unsigned short usv8 __attribute__((ext_vector_type(8)));

__device__ __forceinline__ unsigned short f2bf(float x) {   // RNE f32->bf16
    unsigned u = __float_as_uint(x);
    unsigned r = ((u >> 16) & 1u) + 0x7FFFu;
    return (unsigned short)((u + r) >> 16);
}
__device__ __forceinline__ float bf2f(unsigned short v) {
    return __uint_as_float((unsigned)v << 16);
}

// ---------------- bucketed CSR build (no global data atomics) ----------------

__global__ __launch_bounds__(256) void k_init(int* __restrict__ gcursor) {
    int i = threadIdx.x;
    if (i < NBUCKET) gcursor[i] = i * BSW_CAP;
}

struct P1Shared {
    uint2 stage[P1_CHUNK];              // ((dloc<<17)|src, w) bucket-ordered   32 KB
    unsigned char stage_bkt[P1_CHUNK];  // bucket id per slot                    4 KB
    int cnt[256];
    int lbase[256];
    int gbase[256];
};
struct GemmShared { float sX[64][65]; float sW[64][65]; };

// P1: partition edges into bucket-ordered bsw=(dloc|src, w) with coalesced
// src/ea reads + exp computed here; fused with gemm1.
__global__ __launch_bounds__(256) void k_p1gemm(const int* __restrict__ dst,
                                                const int* __restrict__ srcarr,
                                                const float* __restrict__ ea,
                                                int* gcursor,
                                                uint2* __restrict__ bsw,
                                                const float* __restrict__ X,
                                                const float* __restrict__ W,
                                                float* __restrict__ Y) {
    __shared__ union { P1Shared p; GemmShared g; } sm;
    int t = threadIdx.x;
    if (blockIdx.x < NB_P1) {
        sm.p.cnt[t] = 0;
        __syncthreads();
        int e0 = blockIdx.x * P1_CHUNK;
        unsigned int dr[16];                       // (d<<12)|rank
#pragma unroll
        for (int i = 0; i < 4; ++i) {
            int idx = e0 + (t + i * 256) * 4;
            if (idx + 3 < N_EDGES) {
                int4 d4 = *reinterpret_cast<const int4*>(&dst[idx]);
                int r0 = atomicAdd(&sm.p.cnt[d4.x >> NPB_SHIFT], 1);
                int r1 = atomicAdd(&sm.p.cnt[d4.y >> NPB_SHIFT], 1);
                int r2 = atomicAdd(&sm.p.cnt[d4.z >> NPB_SHIFT], 1);
                int r3 = atomicAdd(&sm.p.cnt[d4.w >> NPB_SHIFT], 1);
                dr[i * 4 + 0] = ((unsigned)d4.x << 12) | (unsigned)r0;
                dr[i * 4 + 1] = ((unsigned)d4.y << 12) | (unsigned)r1;
                dr[i * 4 + 2] = ((unsigned)d4.z << 12) | (unsigned)r2;
                dr[i * 4 + 3] = ((unsigned)d4.w << 12) | (unsigned)r3;
            } else {
#pragma unroll
                for (int k = 0; k < 4; ++k) dr[i * 4 + k] = 0xFFFFFFFFu;
            }
        }
        __syncthreads();
        // exclusive scan of cnt -> lbase; reserve global bucket space
        int v = sm.p.cnt[t];
        sm.p.lbase[t] = v;
        __syncthreads();
        for (int off = 1; off < 256; off <<= 1) {
            int u = (t >= off) ? sm.p.lbase[t - off] : 0;
            __syncthreads();
            sm.p.lbase[t] += u;
            __syncthreads();
        }
        int ex = sm.p.lbase[t] - v;
        if (t < NBUCKET) sm.p.gbase[t] = atomicAdd(&gcursor[t], v);
        __syncthreads();
        sm.p.lbase[t] = ex;
        __syncthreads();
        // stage (dloc|src, w) bucket-sorted; coalesced src/ea reads, exp here
#pragma unroll
        for (int i = 0; i < 4; ++i) {
            int idx = e0 + (t + i * 256) * 4;
            if (idx + 3 < N_EDGES) {
                int4 s4 = *reinterpret_cast<const int4*>(&srcarr[idx]);
                float4 a4 = *reinterpret_cast<const float4*>(&ea[idx]);
                float t0 = a4.x * (1.0f / 200.0f), t1 = a4.y * (1.0f / 200.0f);
                float t2 = a4.z * (1.0f / 200.0f), t3 = a4.w * (1.0f / 200.0f);
                int   ss[4] = {s4.x, s4.y, s4.z, s4.w};
                float ww[4] = {__expf(-t0 * t0), __expf(-t1 * t1),
                               __expf(-t2 * t2), __expf(-t3 * t3)};
#pragma unroll
                for (int k = 0; k < 4; ++k) {
                    unsigned drv = dr[i * 4 + k];
                    int d = drv >> 12, r = drv & 0xFFF;
                    int b = d >> NPB_SHIFT, dloc = d & (NPB - 1);
                    int pos = sm.p.lbase[b] + r;
                    sm.p.stage[pos] = make_uint2(((unsigned)dloc << 17) | (unsigned)ss[k],
                                                 __float_as_uint(ww[k]));
                    sm.p.stage_bkt[pos] = (unsigned char)b;
                }
            }
        }
        __syncthreads();
        // stream out coalesced runs
        int n_valid = min(P1_CHUNK, N_EDGES - e0);
        for (int j = t; j < n_valid; j += 256) {
            int b = sm.p.stage_bkt[j];
            int pos = sm.p.gbase[b] + (j - sm.p.lbase[b]);
            bsw[pos] = sm.p.stage[j];
        }
        return;
    }
    // ---- gemm1: Y = X @ W (f32 out; dinv not known yet) ----
    int rb = (blockIdx.x - NB_P1) * 64;
#pragma unroll
    for (int i = 0; i < 16; ++i) {
        int idx = t + i * 256;
        int r = idx >> 6, c = idx & 63;
        sm.g.sW[r][c] = W[idx];
        int gr = rb + r;
        sm.g.sX[r][c] = (gr < N_NODES) ? X[(size_t)gr * 64 + c] : 0.0f;
    }
    __syncthreads();
    int tr = (t >> 4) * 4;
    int tc = (t & 15) * 4;
    float acc[4][4] = {{0.f}};
#pragma unroll 8
    for (int k = 0; k < 64; ++k) {
        float xv[4], wv[4];
#pragma unroll
        for (int i = 0; i < 4; ++i) xv[i] = sm.g.sX[tr + i][k];
#pragma unroll
        for (int j = 0; j < 4; ++j) wv[j] = sm.g.sW[k][tc + j];
#pragma unroll
        for (int i = 0; i < 4; ++i)
#pragma unroll
            for (int j = 0; j < 4; ++j) acc[i][j] = fmaf(xv[i], wv[j], acc[i][j]);
    }
#pragma unroll
    for (int i = 0; i < 4; ++i) {
        int gr = rb + tr + i;
        if (gr < N_NODES) {
            float4 v = make_float4(acc[i][0], acc[i][1], acc[i][2], acc[i][3]);
            *reinterpret_cast<float4*>(&Y[(size_t)gr * 64 + tc]) = v;
        }
    }
}

// P2: pure-streaming per-bucket build. LDS hist -> scan -> LDS-cursor scatter.
__global__ __launch_bounds__(1024) void k_p2(const uint2* __restrict__ bsw,
                                             const int* __restrict__ gcursor,
                                             int2* __restrict__ rowinfo,
                                             int2* __restrict__ csr,
                                             float* __restrict__ dinv) {
    __shared__ int cnt[NPB];
    __shared__ int prp[NPB];
    __shared__ int cur[NPB];
    __shared__ float degw[NPB];
    int t = threadIdx.x;
    int b = blockIdx.x;
    if (t < NPB) { cnt[t] = 0; degw[t] = 0.0f; }
    __syncthreads();
    int segb = b * BSW_CAP;
    int sege = gcursor[b];                 // = segb + bucket count
    int pbase = b * CSR_CAP;
    for (int j = segb + t; j < sege; j += 1024)
        atomicAdd(&cnt[bsw[j].x >> 17], 1);
    __syncthreads();
    int raw = (t < NPB) ? cnt[t] : 0;
    int pad = (raw + 7) & ~7;
    if (t < NPB) prp[t] = pad;
    __syncthreads();
    for (int off = 1; off < NPB; off <<= 1) {
        int u = (t >= off && t < NPB) ? prp[t - off] : 0;
        __syncthreads();
        if (t < NPB) prp[t] += u;
        __syncthreads();
    }
    if (t < NPB) { prp[t] -= pad; cur[t] = prp[t]; }   // exclusive base + cursor
    __syncthreads();
    int node = (b << NPB_SHIFT) + t;
    if (t < NPB && node < N_NODES)
        rowinfo[node] = make_int2(pbase + prp[t], pad >> 3);
    for (int j = segb + t; j < sege; j += 1024) {
        uint2 v = bsw[j];
        int dloc = (int)(v.x >> 17);
        int src  = (int)(v.x & 0x1FFFFu);
        int pos = atomicAdd(&cur[dloc], 1);
        csr[pbase + pos] = make_int2(src, (int)v.y);
        atomicAdd(&degw[dloc], __uint_as_float(v.y));
    }
    __syncthreads();
    if (t < NPB && node < N_NODES) {
        dinv[node] = rsqrtf(1.0f + degw[t]);
        int begin = pbase + prp[t];
        for (int j = raw; j < pad; ++j) csr[begin + j] = make_int2(node, 0);
    }
}

// XWs[i,f] = bf16(dinv[i] * XW[i,f])  — scale+convert stream (8 elems/thread)
__global__ __launch_bounds__(256) void k_scale(const float* __restrict__ XW,
                                               const float* __restrict__ dinv,
                                               unsigned short* __restrict__ XWs) {
    int g = blockIdx.x * 256 + threadIdx.x;
    int base = g * 8;
    if (base >= N_NODES * 64) return;
    float d = dinv[base >> 6];
    float4 v0 = *reinterpret_cast<const float4*>(XW + base);
    float4 v1 = *reinterpret_cast<const float4*>(XW + base + 4);
    usv8 r;
    r.s0 = f2bf(d * v0.x); r.s1 = f2bf(d * v0.y);
    r.s2 = f2bf(d * v0.z); r.s3 = f2bf(d * v0.w);
    r.s4 = f2bf(d * v1.x); r.s5 = f2bf(d * v1.y);
    r.s6 = f2bf(d * v1.z); r.s7 = f2bf(d * v1.w);
    *reinterpret_cast<usv8*>(XWs + base) = r;
}

// ---------------- dense compute ----------------

// gemm2: Y = X @ W with epilogue  XWs[gr,:] = bf16(dinv[gr] * Y[gr,:])
__global__ __launch_bounds__(256) void k_gemm64s(const float* __restrict__ X,
                                                 const float* __restrict__ W,
                                                 const float* __restrict__ dinv,
                                                 unsigned short* __restrict__ XWs) {
    __shared__ float sX[64][65];
    __shared__ float sW[64][65];
    int t = threadIdx.x;
    int rb = blockIdx.x * 64;
#pragma unroll
    for (int i = 0; i < 16; ++i) {
        int idx = t + i * 256;
        int r = idx >> 6, c = idx & 63;
        sW[r][c] = W[idx];
        int gr = rb + r;
        sX[r][c] = (gr < N_NODES) ? X[(size_t)gr * 64 + c] : 0.0f;
    }
    __syncthreads();
    int tr = (t >> 4) * 4;
    int tc = (t & 15) * 4;
    float acc[4][4] = {{0.f}};
#pragma unroll 8
    for (int k = 0; k < 64; ++k) {
        float xv[4], wv[4];
#pragma unroll
        for (int i = 0; i < 4; ++i) xv[i] = sX[tr + i][k];
#pragma unroll
        for (int j = 0; j < 4; ++j) wv[j] = sW[k][tc + j];
#pragma unroll
        for (int i = 0; i < 4; ++i)
#pragma unroll
            for (int j = 0; j < 4; ++j) acc[i][j] = fmaf(xv[i], wv[j], acc[i][j]);
    }
#pragma unroll
    for (int i = 0; i < 4; ++i) {
        int gr = rb + tr + i;
        if (gr < N_NODES) {
            float d = dinv[gr];
            ushort4 v;
            v.x = f2bf(d * acc[i][0]); v.y = f2bf(d * acc[i][1]);
            v.z = f2bf(d * acc[i][2]); v.w = f2bf(d * acc[i][3]);
            *reinterpret_cast<ushort4*>(&XWs[((unsigned)gr << 6) + tc]) = v;
        }
    }
}

// one wave per node, lane = feature. CSR path fully scalarized (s_load via K$).
// MODE 0: OUT[i,f] = relu(di*(selfs+esum) + bias)          (f32 row out)
// MODE 1: h = relu(...); OUT[i] = di * dot(h, W3)          (scalar xw3s out)
template <int MODE>
__global__ __launch_bounds__(256) void k_agg64(const unsigned short* __restrict__ XWs,
                                               const int* __restrict__ csr_i,
                                               const int2* __restrict__ rowinfo,
                                               const float* __restrict__ dinv,
                                               const float* __restrict__ bias,
                                               float* __restrict__ OUT,
                                               const float* __restrict__ W3) {
    int wid0 = (blockIdx.x * 256 + threadIdx.x) >> 6;
    if (wid0 >= N_NODES) return;                     // wave-uniform exit
    int wid = __builtin_amdgcn_readfirstlane(wid0);  // explicit SGPR
    unsigned f = threadIdx.x & 63;
    float di = dinv[wid];                            // scalar load
    float selfs = bf2f(XWs[((unsigned)wid << 6) + f]);
    int2 ri = rowinfo[wid];                          // scalar load
    int rbase = __builtin_amdgcn_readfirstlane(ri.x);
    int nb    = __builtin_amdgcn_readfirstlane(ri.y);
    const int* pc = csr_i + ((size_t)rbase * 2);     // uniform pointer
    float a[8] = {0.f, 0.f, 0.f, 0.f, 0.f, 0.f, 0.f, 0.f};
    for (int it = 0; it < nb; ++it, pc += 16) {
        int s0 = pc[0],  w0 = pc[1],  s1 = pc[2],  w1 = pc[3];
        int s2 = pc[4],  w2 = pc[5],  s3 = pc[6],  w3 = pc[7];
        int s4 = pc[8],  w4 = pc[9],  s5 = pc[10], w5 = pc[11];
        int s6 = pc[12], w6 = pc[13], s7 = pc[14], w7 = pc[15];
        float r0 = bf2f(XWs[((unsigned)s0 << 6) + f]);
        float r1 = bf2f(XWs[((unsigned)s1 << 6) + f]);
        float r2 = bf2f(XWs[((unsigned)s2 << 6) + f]);
        float r3 = bf2f(XWs[((unsigned)s3 << 6) + f]);
        float r4 = bf2f(XWs[((unsigned)s4 << 6) + f]);
        float r5 = bf2f(XWs[((unsigned)s5 << 6) + f]);
        float r6 = bf2f(XWs[((unsigned)s6 << 6) + f]);
        float r7 = bf2f(XWs[((unsigned)s7 << 6) + f]);
        a[0] = fmaf(__int_as_float(w0), r0, a[0]);
        a[1] = fmaf(__int_as_float(w1), r1, a[1]);
        a[2] = fmaf(__int_as_float(w2), r2, a[2]);
        a[3] = fmaf(__int_as_float(w3), r3, a[3]);
        a[4] = fmaf(__int_as_float(w4), r4, a[4]);
        a[5] = fmaf(__int_as_float(w5), r5, a[5]);
        a[6] = fmaf(__int_as_float(w6), r6, a[6]);
        a[7] = fmaf(__int_as_float(w7), r7, a[7]);
    }
    float esum = ((a[0] + a[1]) + (a[2] + a[3])) + ((a[4] + a[5]) + (a[6] + a[7]));
    float acc = di * (selfs + esum) + bias[f];
    acc = fmaxf(acc, 0.0f);
    if (MODE == 0) {
        OUT[((unsigned)wid << 6) + f] = acc;
    } else {
        float v = acc * W3[f];
#pragma unroll
        for (int off = 32; off > 0; off >>= 1) v += __shfl_down(v, off, 64);
        if (f == 0) OUT[wid] = di * v;          // store xw3s = dinv * xw3
    }
}

// out[i] = b3 + di*(xw3s[i] + sum_e w_e*xw3s[src_e])   (raw w, scaled table)
__global__ __launch_bounds__(256) void k_agg_scalar(const float* __restrict__ xw3s,
                                                    const int2* __restrict__ csr,
                                                    const int2* __restrict__ rowinfo,
                                                    const float* __restrict__ dinv,
                                                    const float* __restrict__ b3,
                                                    float* __restrict__ out) {
    int i = blockIdx.x * 256 + threadIdx.x;
    if (i >= N_NODES) return;
    float di = dinv[i];
    int2 ri = rowinfo[i];
    const iv4* p = reinterpret_cast<const iv4*>(csr + ri.x);
    int nb = ri.y;
    float a0 = 0.f, a1 = 0.f, a2 = 0.f, a3 = 0.f;
    for (int it = 0; it < nb; ++it, p += 4) {
        iv4 q0 = __builtin_nontemporal_load(p);
        iv4 q1 = __builtin_nontemporal_load(p + 1);
        iv4 q2 = __builtin_nontemporal_load(p + 2);
        iv4 q3 = __builtin_nontemporal_load(p + 3);
        a0 = fmaf(__int_as_float(q0.y), xw3s[q0.x], a0);
        a1 = fmaf(__int_as_float(q0.w), xw3s[q0.z], a1);
        a2 = fmaf(__int_as_float(q1.y), xw3s[q1.x], a2);
        a3 = fmaf(__int_as_float(q1.w), xw3s[q1.z], a3);
        a0 = fmaf(__int_as_float(q2.y), xw3s[q2.x], a0);
        a1 = fmaf(__int_as_float(q2.w), xw3s[q2.z], a1);
        a2 = fmaf(__int_as_float(q3.y), xw3s[q3.x], a2);
        a3 = fmaf(__int_as_float(q3.w), xw3s[q3.z], a3);
    }
    out[i] = di * (xw3s[i] + (a0 + a1) + (a2 + a3)) + b3[0];
}

// ---------------- launch ----------------

extern "C" void kernel_launch(void* const* d_in, const int* in_sizes, int n_in,
                              void* d_out, int out_size, void* d_ws, size_t ws_size,
                              hipStream_t stream) {
    const float* x  = (const float*)d_in[0];
    const int*   ei = (const int*)d_in[1];     // int32 per harness contract
    const float* ea = (const float*)d_in[2];
    const float* W1 = (const float*)d_in[3];
    const float* b1 = (const float*)d_in[4];
    const float* W2 = (const float*)d_in[5];
    const float* b2 = (const float*)d_in[6];
    const float* W3 = (const float*)d_in[7];
    const float* b3 = (const float*)d_in[8];
    float* out = (float*)d_out;
    const int* srcarr = ei;
    const int* dstarr = ei + N_EDGES;

    char* ws = (char*)d_ws;
    size_t off = 0;
    auto alloc = [&](size_t bytes) -> void* {
        void* p = ws + off;
        off = (off + bytes + 255) & ~(size_t)255;
        return p;
    };
    float* dinv     = (float*)alloc((size_t)N_NODES * 4);
    int2*  rowinfo  = (int2*) alloc((size_t)N_NODES * 8);
    int*   gcursor  = (int*)  alloc(NBUCKET * 4);
    float* xw3s     = (float*)alloc((size_t)N_NODES * 4);
    // bsw (14.5 MB; dead after P2) shares its region with XWs1 (12.8 MB)
    void*  region   = alloc((size_t)NBUCKET * BSW_CAP * 8);
    uint2*          bsw  = (uint2*)region;
    unsigned short* XWs1 = (unsigned short*)region;
    int2*  csr      = (int2*) alloc((size_t)NBUCKET * CSR_CAP * 8);
    float* bufA     = (float*)alloc((size_t)N_NODES * 64 * 4);   // gemm1 out; reused as XWs2
    float* bufB     = (float*)alloc((size_t)N_NODES * 64 * 4);
    unsigned short* XWs2 = (unsigned short*)bufA;  // bufA dead after k_scale reads it

    const int nbW = N_NODES / 4;             // 25000
    const int nbN = (N_NODES + 255) / 256;   // 391
    const int nbS = (N_NODES * 64 / 8 + 255) / 256;   // 3125 scale blocks

    k_init<<<1, 256, 0, stream>>>(gcursor);
    k_p1gemm<<<NB_P1 + NBG, 256, 0, stream>>>(dstarr, srcarr, ea, gcursor,
                                              bsw, x, W1, bufA);
    k_p2<<<NBUCKET, 1024, 0, stream>>>(bsw, gcursor, rowinfo, csr, dinv);
    k_scale<<<nbS, 256, 0, stream>>>(bufA, dinv, XWs1);   // overwrites bsw region

    k_agg64<0><<<nbW, 256, 0, stream>>>(XWs1, (const int*)csr, rowinfo, dinv, b1, bufB, nullptr);
    k_gemm64s<<<NBG, 256, 0, stream>>>(bufB, W2, dinv, XWs2);   // overwrites bufA
    k_agg64<1><<<nbW, 256, 0, stream>>>(XWs2, (const int*)csr, rowinfo, dinv, b2, xw3s, W3);
    k_agg_scalar<<<nbN, 256, 0, stream>>>(xw3s, csr, rowinfo, dinv, b3, out);
}